// Round 15
// baseline (128.921 us; speedup 1.0000x reference)
//
#include <hip/hip_runtime.h>
#include <cstddef>

// Block-cooperative MFMA MixModel, 32 rows/tile (R15 = R14 + coalesced output):
//   GEMM1 SWAPPED (R13/R14-verified): lane holds h[row=ln][4k] -> tanh_pade ->
//     cvt_pk -> ds_write_b64.
//   GEMM2 SWAPPED, 144-col padded layout (R14-verified): lane (ln,lg) of tile g
//     holds row ln, pair i=2g+(lg>>1), parity lg&1. rb serial (acc2[3]).
//   EPILOGUE IN REGISTERS (R14-verified formula), but res -> res_sh[32][38] f32
//     (scalar b32, 16-bank spread) instead of scattered global stores.
//     R14 BUG: per-lane 4B global stores across 144B-strided rows -> write
//     amplification (WRITE 129MB, RFO FETCH +28MB). Fixed by LDS staging +
//     R13-proven copy-out: 576 float2 items, ds_read_b64 + coalesced store.
//   LDS 20736 B; 4 barriers/tile.

typedef __attribute__((ext_vector_type(8))) __bf16 bf16x8;
typedef __attribute__((ext_vector_type(8))) short short8;
typedef __attribute__((ext_vector_type(4))) float f32x4;

__device__ __forceinline__ unsigned short f2bf(float f) {
    // manual RNE float->bf16 (init-time only)
    unsigned int u = __float_as_uint(f);
    unsigned int r = (u + 0x7FFFu + ((u >> 16) & 1u)) >> 16;
    return (unsigned short)r;
}

__device__ __forceinline__ unsigned int cvt_pk_bf16(float lo, float hi) {
    // gfx950 packed convert (R11/R13-verified)
    unsigned int r;
    asm("v_cvt_pk_bf16_f32 %0, %1, %2" : "=v"(r) : "v"(lo), "v"(hi));
    return r;
}

// --- mfma wrapper: tolerate either V8bf16 or V8i16 builtin signature ---
template <typename A>
__device__ __forceinline__ auto mfma_try(A a, A b, f32x4 c, int)
    -> decltype(__builtin_amdgcn_mfma_f32_16x16x32_bf16(a, b, c, 0, 0, 0)) {
    return __builtin_amdgcn_mfma_f32_16x16x32_bf16(a, b, c, 0, 0, 0);
}
template <typename A>
__device__ __forceinline__ f32x4 mfma_try(A a, A b, f32x4 c, long) {
    return __builtin_amdgcn_mfma_f32_16x16x32_bf16(
        __builtin_bit_cast(short8, a), __builtin_bit_cast(short8, b), c, 0, 0, 0);
}
__device__ __forceinline__ f32x4 mfma_bf16(short8 a, short8 b, f32x4 c) {
    return mfma_try(__builtin_bit_cast(bf16x8, a), __builtin_bit_cast(bf16x8, b), c, 0);
}

__device__ __forceinline__ float tanh_pade(float x) {
    // clamped Pade(3,2) (R11/R13-verified)
    const float t = fminf(fmaxf(x, -3.0f), 3.0f);
    const float s = t * t;
    return __fdividef(t * (27.0f + s), fmaf(9.0f, s, 27.0f));
}

__global__ __launch_bounds__(256, 4) void mixmodel_mfma15(
    const float* __restrict__ u,      // N*36
    const float* __restrict__ reg1,   // 6
    const float* __restrict__ reg2,   // 4
    const float* __restrict__ W1,     // 18*128
    const float* __restrict__ b1,     // 128
    const float* __restrict__ W2a,    // 128*54
    const float* __restrict__ b2a,    // 54
    const float* __restrict__ W2b,    // 128*72
    const float* __restrict__ b2b,    // 72
    float* __restrict__ out,          // N*36
    int N, int ntiles)
{
    __shared__ __align__(16) float          u_ext[32 * 40];   // 5120 B
    __shared__ __align__(16) unsigned short h_sh[32 * 136];   // 8704 B (verified layout)
    __shared__ __align__(16) unsigned short u_bf[32 * 32];    // 2048 B
    __shared__ __align__(16) float          res_sh[32 * 38];  // 4864 B (stride 38: float2-aligned, 16-bank write spread)
    // total = 20736 B

    const int tid = threadIdx.x;
    const int wid = tid >> 6;
    const int l   = tid & 63;
    const int ln  = l & 15;
    const int lg  = l >> 4;
    const int nb  = wid * 32;        // GEMM1 column base

    reinterpret_cast<unsigned int*>(u_bf)[tid]       = 0u;
    reinterpret_cast<unsigned int*>(u_bf)[tid + 256] = 0u;
    __syncthreads();

    // ---- GEMM1 weights (swapped; R13-verified) ----
    short8 b1f[2];
    f32x4 bias1v[2];
#pragma unroll
    for (int t = 0; t < 2; ++t) {
        const int n = nb + t * 16 + ln;
        short8 v;
#pragma unroll
        for (int j = 0; j < 8; ++j) {
            const int k = lg * 8 + j;
            const float w = (k < 18) ? W1[k * 128 + n] : 0.0f;
            v[j] = (short)f2bf(w);
        }
        b1f[t] = v;
        bias1v[t] = *reinterpret_cast<const f32x4*>(&b1[nb + t * 16 + lg * 4]);
    }

    // ---- GEMM2 weights (swapped, 144-col; R14-verified): tiles 3/2/2/2 ----
    const int NT    = (wid == 0) ? 3 : 2;
    const int gbase = (wid == 0) ? 0 : 2 * wid + 1;  // {0,3,5,7}
    short8 b2f[3][4];
    f32x4 bias2v[3];
#pragma unroll
    for (int tl = 0; tl < 3; ++tl) {
        if (tl < NT) {
            const int g  = gbase + tl;
            const int nf = 16 * g + ln;          // A-operand row index (weights)
            const int q  = nf >> 3, m = nf & 7;
#pragma unroll
            for (int kk = 0; kk < 4; ++kk) {
                short8 w2;
#pragma unroll
                for (int j = 0; j < 8; ++j) {
                    const int k = kk * 32 + lg * 8 + j;
                    float w;
                    if (m < 3)       w = W2a[k * 54 + 3 * q + m];
                    else if (m == 3) w = 0.0f;
                    else             w = W2b[k * 72 + 4 * q + (m - 4)];
                    w2[j] = (short)f2bf(w);
                }
                b2f[tl][kk] = w2;
            }
            f32x4 bv;
#pragma unroll
            for (int r = 0; r < 4; ++r) {
                const int n  = 16 * g + 4 * lg + r;
                const int qq = n >> 3, mm = n & 7;
                bv[r] = (mm < 3) ? b2a[3 * qq + mm]
                                 : (mm == 3 ? 0.0f : b2b[4 * qq + (mm - 4)]);
            }
            bias2v[tl] = bv;
        }
    }

    // ---- per-lane parity-selected regression coefficients (R14-verified) ----
    const bool odd = (lg & 1) != 0;
    const float cb  = odd ? reg2[0] : reg1[0];
    const float cue = odd ? 0.0f    : reg1[1];
    const float cuo = odd ? reg2[1] : reg1[2];
    const float c1  = odd ? reg2[2] : reg1[3];
    const float c2c = odd ? reg2[3] : reg1[4];
    const float c3  = odd ? 0.0f    : reg1[5];

    const float4* ug = reinterpret_cast<const float4*>(u);
    const long fmax4 = (long)N * 9 - 1;
    const int gs = gridDim.x;

    // ---- staging maps (R8-verified) ----
    const int row0 = tid / 9,          c0 = tid - row0 * 9;
    const int row1 = (256 + tid) / 9,  c1s = (256 + tid) - row1 * 9;
    const int hrow = (tid - 192) >> 1, hside = tid & 1;

    float4 pf0, pf1; float2 pfh;
    {
        const int r0 = blockIdx.x * 32;
        long g0 = (long)r0 * 9 + tid; if (g0 > fmax4) g0 = fmax4;
        pf0 = ug[g0];
        if (tid < 32) {
            long g1 = (long)r0 * 9 + 256 + tid; if (g1 > fmax4) g1 = fmax4;
            pf1 = ug[g1];
        }
        if (tid >= 192) {
            int rr = r0 + hrow; if (rr > N - 1) rr = N - 1;
            pfh = *reinterpret_cast<const float2*>(u + (size_t)rr * 36 + (hside ? 0 : 34));
        }
    }

    for (int tile = blockIdx.x; tile < ntiles; tile += gs) {
        // ---- stage u_ext / u_bf (cvt_pk); prefetch next (R13-verified) ----
        {
            float* dst = &u_ext[row0 * 40 + 2 + c0 * 4];
            reinterpret_cast<float2*>(dst)[0] = make_float2(pf0.x, pf0.y);
            reinterpret_cast<float2*>(dst)[1] = make_float2(pf0.z, pf0.w);
            reinterpret_cast<unsigned int*>(u_bf)[row0 * 16 + c0] =
                cvt_pk_bf16(pf0.x, pf0.z);
            if (tid < 32) {
                float* dst1 = &u_ext[row1 * 40 + 2 + c1s * 4];
                reinterpret_cast<float2*>(dst1)[0] = make_float2(pf1.x, pf1.y);
                reinterpret_cast<float2*>(dst1)[1] = make_float2(pf1.z, pf1.w);
                reinterpret_cast<unsigned int*>(u_bf)[row1 * 16 + c1s] =
                    cvt_pk_bf16(pf1.x, pf1.z);
            }
            if (tid >= 192)
                *reinterpret_cast<float2*>(&u_ext[hrow * 40 + (hside ? 38 : 0)]) = pfh;

            if (tile + gs < ntiles) {
                const int r0n = (tile + gs) * 32;
                long g0 = (long)r0n * 9 + tid; if (g0 > fmax4) g0 = fmax4;
                pf0 = ug[g0];
                if (tid < 32) {
                    long g1 = (long)r0n * 9 + 256 + tid; if (g1 > fmax4) g1 = fmax4;
                    pf1 = ug[g1];
                }
                if (tid >= 192) {
                    int rr = r0n + hrow; if (rr > N - 1) rr = N - 1;
                    pfh = *reinterpret_cast<const float2*>(u + (size_t)rr * 36 + (hside ? 0 : 34));
                }
            }
        }
        __syncthreads();  // bar1: u ready

        // ---- GEMM1 SWAPPED (R13-verified): tanh_pade + cvt_pk -> ds_write_b64 ----
#pragma unroll
        for (int rb = 0; rb < 2; ++rb) {
            const short8 a1 = *reinterpret_cast<const short8*>(
                &u_bf[(rb * 16 + ln) * 32 + lg * 8]);
#pragma unroll
            for (int t = 0; t < 2; ++t) {
                const f32x4 h4 = mfma_bf16(b1f[t], a1, bias1v[t]);   // SWAPPED -> h^T
                const unsigned int p0 =
                    cvt_pk_bf16(tanh_pade(h4[0]), tanh_pade(h4[1]));
                const unsigned int p1 =
                    cvt_pk_bf16(tanh_pade(h4[2]), tanh_pade(h4[3]));
                *reinterpret_cast<uint2*>(
                    &h_sh[(rb * 16 + ln) * 136 + nb + t * 16 + lg * 4]) =
                    make_uint2(p0, p1);
            }
        }
        __syncthreads();  // bar2: h ready

        // ---- GEMM2 SWAPPED + in-register epilogue -> res_sh (R14 formula) ----
#pragma unroll
        for (int rb = 0; rb < 2; ++rb) {
            const int arow = rb * 16 + ln;

            short8 a2f[4];
#pragma unroll
            for (int kk = 0; kk < 4; ++kk)
                a2f[kk] = *reinterpret_cast<const short8*>(
                    &h_sh[arow * 136 + kk * 32 + lg * 8]);

            f32x4 acc2[3];
#pragma unroll
            for (int tl = 0; tl < 3; ++tl)
                if (tl < NT) acc2[tl] = bias2v[tl];
#pragma unroll
            for (int kk = 0; kk < 4; ++kk)
#pragma unroll
                for (int tl = 0; tl < 3; ++tl)
                    if (tl < NT)
                        acc2[tl] = mfma_bf16(b2f[tl][kk], a2f[kk], acc2[tl]);  // SWAPPED

#pragma unroll
            for (int tl = 0; tl < 3; ++tl) {
                if (tl < NT) {
                    const int i = 2 * (gbase + tl) + (lg >> 1);
                    const float* ub = &u_ext[arow * 40 + 2 * i];
                    const float2 v0 = *reinterpret_cast<const float2*>(ub);      // um2, uA
                    const float2 v1 = *reinterpret_cast<const float2*>(ub + 2);  // ue,  uo
                    const float2 v2 = *reinterpret_cast<const float2*>(ub + 4);  // up2, uC

                    const float um2 = v0.x, uA = v0.y;
                    const float ue  = v1.x, uo = v1.y;
                    const float up2 = v2.x, uC = v2.y;

                    const float pa = odd ? ue : um2;   // * uA
                    const float pb = odd ? ue : uA;    // * up2

                    float res = acc2[tl][0] + cb;
                    res = fmaf(acc2[tl][1], uA, res);
                    res = fmaf(acc2[tl][2] + cuo, uo, res);
                    res = fmaf(acc2[tl][3], uC, res);        // even lanes: acc[3]==0
                    res = fmaf(c1,  uA * pa,  res);
                    res = fmaf(c2c, pb * up2, res);
                    res = fmaf(ue,  fmaf(c3, uo, cue), res);

                    res_sh[arow * 38 + 2 * i + (odd ? 1 : 0)] = res;
                }
            }
        }
        __syncthreads();  // bar3: res ready

        // ---- copy-out: 576 float2 items, coalesced (R13-proven output pattern) ----
        const int r0 = tile * 32;
#pragma unroll
        for (int s = 0; s < 3; ++s) {
            const int w = s * 256 + tid;
            if (w < 576) {
                const int row = w / 18;
                const int p   = w - row * 18;
                const int rg  = r0 + row;
                if (rg < N) {
                    const float2 rv =
                        *reinterpret_cast<const float2*>(&res_sh[row * 38 + 2 * p]);
                    *reinterpret_cast<float2*>(out + (size_t)rg * 36 + 2 * p) = rv;
                }
            }
        }
        __syncthreads();  // bar4: buffers free for next staging
    }
}

extern "C" void kernel_launch(void* const* d_in, const int* in_sizes, int n_in,
                              void* d_out, int out_size, void* d_ws, size_t ws_size,
                              hipStream_t stream) {
    // d_in order: t, u, reg1, reg2, W1, b1, W2a, b2a, W2b, b2b
    const float* u    = (const float*)d_in[1];
    const float* reg1 = (const float*)d_in[2];
    const float* reg2 = (const float*)d_in[3];
    const float* W1   = (const float*)d_in[4];
    const float* b1   = (const float*)d_in[5];
    const float* W2a  = (const float*)d_in[6];
    const float* b2a  = (const float*)d_in[7];
    const float* W2b  = (const float*)d_in[8];
    const float* b2b  = (const float*)d_in[9];
    float* out = (float*)d_out;

    const int N = in_sizes[1] / 36;
    const int ntiles = (N + 31) / 32;
    int grid = ntiles < 1024 ? ntiles : 1024;
    if (grid < 1) grid = 1;
    mixmodel_mfma15<<<grid, 256, 0, stream>>>(u, reg1, reg2, W1, b1,
                                              W2a, b2a, W2b, b2b, out, N, ntiles);
}

// Round 16
// 101.075 us; speedup vs baseline: 1.2755x; 1.2755x over previous
//
#include <hip/hip_runtime.h>
#include <cstddef>

// Block-cooperative MFMA MixModel, 32 rows/tile (R16 = R15 minus the spill):
//   GEMM1 SWAPPED (R13/R15-verified): lane holds h[row=ln][4k] -> tanh_pade ->
//     cvt_pk -> ds_write_b64.
//   GEMM2 SWAPPED, 144-col padded layout (R14/R15-verified epilogue ownership):
//     tiles 0..7 in registers, waves get {2w,2w+1} -> b2f[2][4]=32 VGPR UNIFORM.
//     Tile 8 (pairs 16,17) weights in LDS (4KB, fragment-order, written once);
//     wave0 computes tile8@rb0, wave1 tile8@rb1 -> no wave needs 3 reg tiles.
//     (R14/R15 BUG: 3-tile wave needed ~140 VGPR > 128 cap -> scratch spill,
//      FETCH/WRITE +70MB each. This removes the deficit structurally.)
//   EPILOGUE IN REGISTERS (R15-verified) -> res_sh[32][38] -> coalesced copy-out.
//   LDS 24832 B -> 6 blocks/CU; 4 barriers/tile.

typedef __attribute__((ext_vector_type(8))) __bf16 bf16x8;
typedef __attribute__((ext_vector_type(8))) short short8;
typedef __attribute__((ext_vector_type(4))) float f32x4;

__device__ __forceinline__ unsigned short f2bf(float f) {
    unsigned int u = __float_as_uint(f);
    unsigned int r = (u + 0x7FFFu + ((u >> 16) & 1u)) >> 16;
    return (unsigned short)r;
}

__device__ __forceinline__ unsigned int cvt_pk_bf16(float lo, float hi) {
    unsigned int r;
    asm("v_cvt_pk_bf16_f32 %0, %1, %2" : "=v"(r) : "v"(lo), "v"(hi));
    return r;
}

// --- mfma wrapper: tolerate either V8bf16 or V8i16 builtin signature ---
template <typename A>
__device__ __forceinline__ auto mfma_try(A a, A b, f32x4 c, int)
    -> decltype(__builtin_amdgcn_mfma_f32_16x16x32_bf16(a, b, c, 0, 0, 0)) {
    return __builtin_amdgcn_mfma_f32_16x16x32_bf16(a, b, c, 0, 0, 0);
}
template <typename A>
__device__ __forceinline__ f32x4 mfma_try(A a, A b, f32x4 c, long) {
    return __builtin_amdgcn_mfma_f32_16x16x32_bf16(
        __builtin_bit_cast(short8, a), __builtin_bit_cast(short8, b), c, 0, 0, 0);
}
__device__ __forceinline__ f32x4 mfma_bf16(short8 a, short8 b, f32x4 c) {
    return mfma_try(__builtin_bit_cast(bf16x8, a), __builtin_bit_cast(bf16x8, b), c, 0);
}

__device__ __forceinline__ float tanh_pade(float x) {
    const float t = fminf(fmaxf(x, -3.0f), 3.0f);
    const float s = t * t;
    return __fdividef(t * (27.0f + s), fmaf(9.0f, s, 27.0f));
}

// 144-col internal map: col n = 8q+m; m<3 -> W2a[:,3q+m]; m==3 -> 0; m>=4 -> W2b[:,4q+m-4]
__device__ __forceinline__ float w2_at(const float* W2a, const float* W2b, int k, int n) {
    const int q = n >> 3, m = n & 7;
    if (m < 3)  return W2a[k * 54 + 3 * q + m];
    if (m == 3) return 0.0f;
    return W2b[k * 72 + 4 * q + (m - 4)];
}
__device__ __forceinline__ float b2_at(const float* b2a, const float* b2b, int n) {
    const int q = n >> 3, m = n & 7;
    if (m < 3)  return b2a[3 * q + m];
    if (m == 3) return 0.0f;
    return b2b[4 * q + (m - 4)];
}

__global__ __launch_bounds__(256, 4) void mixmodel_mfma16(
    const float* __restrict__ u,      // N*36
    const float* __restrict__ reg1,   // 6
    const float* __restrict__ reg2,   // 4
    const float* __restrict__ W1,     // 18*128
    const float* __restrict__ b1,     // 128
    const float* __restrict__ W2a,    // 128*54
    const float* __restrict__ b2a,    // 54
    const float* __restrict__ W2b,    // 128*72
    const float* __restrict__ b2b,    // 72
    float* __restrict__ out,          // N*36
    int N, int ntiles)
{
    __shared__ __align__(16) float          u_ext[32 * 40];   // 5120 B
    __shared__ __align__(16) unsigned short h_sh[32 * 136];   // 8704 B (verified layout)
    __shared__ __align__(16) unsigned short u_bf[32 * 32];    // 2048 B
    __shared__ __align__(16) float          res_sh[32 * 38];  // 4864 B (R15-verified)
    __shared__ __align__(16) unsigned short w8_sh[4 * 512];   // 4096 B: tile-8 W2 fragments
    // total = 24832 B -> 6 blocks/CU

    const int tid = threadIdx.x;
    const int wid = tid >> 6;
    const int l   = tid & 63;
    const int ln  = l & 15;
    const int lg  = l >> 4;
    const int nb  = wid * 32;        // GEMM1 column base

    // ---- one-time LDS init: u_bf pads + tile-8 weight fragments ----
    reinterpret_cast<unsigned int*>(u_bf)[tid]       = 0u;
    reinterpret_cast<unsigned int*>(u_bf)[tid + 256] = 0u;
    {
        // thread tid -> fragment (kk = tid>>6, lane l8 = tid&63): 8 bf16, exact
        // order the GEMM2 b128 read consumes (fragment identity).
        const int kk8 = tid >> 6, l8 = tid & 63;
        const int ln8 = l8 & 15, lg8 = l8 >> 4;
        unsigned int pk[4];
#pragma unroll
        for (int jj = 0; jj < 4; ++jj) {
            const int k0 = kk8 * 32 + lg8 * 8 + 2 * jj;
            const float w0 = w2_at(W2a, W2b, k0,     128 + ln8);
            const float w1 = w2_at(W2a, W2b, k0 + 1, 128 + ln8);
            pk[jj] = (unsigned int)f2bf(w0) | ((unsigned int)f2bf(w1) << 16);
        }
        unsigned int* dst = reinterpret_cast<unsigned int*>(&w8_sh[kk8 * 512 + l8 * 8]);
        dst[0] = pk[0]; dst[1] = pk[1]; dst[2] = pk[2]; dst[3] = pk[3];
    }
    __syncthreads();

    // ---- GEMM1 weights (swapped; R13-verified) ----
    short8 b1f[2];
    f32x4 bias1v[2];
#pragma unroll
    for (int t = 0; t < 2; ++t) {
        const int n = nb + t * 16 + ln;
        short8 v;
#pragma unroll
        for (int j = 0; j < 8; ++j) {
            const int k = lg * 8 + j;
            const float w = (k < 18) ? W1[k * 128 + n] : 0.0f;
            v[j] = (short)f2bf(w);
        }
        b1f[t] = v;
        bias1v[t] = *reinterpret_cast<const f32x4*>(&b1[nb + t * 16 + lg * 4]);
    }

    // ---- GEMM2 register weights: tiles {2*wid, 2*wid+1} ----
    short8 b2f[2][4];
    f32x4 bias2v[2];
#pragma unroll
    for (int tl = 0; tl < 2; ++tl) {
        const int g  = 2 * wid + tl;
        const int nf = 16 * g + ln;
#pragma unroll
        for (int kk = 0; kk < 4; ++kk) {
            short8 w2;
#pragma unroll
            for (int j = 0; j < 8; ++j)
                w2[j] = (short)f2bf(w2_at(W2a, W2b, kk * 32 + lg * 8 + j, nf));
            b2f[tl][kk] = w2;
        }
        f32x4 bv;
#pragma unroll
        for (int r = 0; r < 4; ++r)
            bv[r] = b2_at(b2a, b2b, 16 * g + 4 * lg + r);
        bias2v[tl] = bv;
    }
    // tile-8 bias (used by wave 0 @ rb0, wave 1 @ rb1)
    f32x4 bias8v;
#pragma unroll
    for (int r = 0; r < 4; ++r)
        bias8v[r] = b2_at(b2a, b2b, 128 + 4 * lg + r);

    // ---- per-lane parity-selected regression coefficients (R14/R15-verified) ----
    const bool odd = (lg & 1) != 0;
    const float cb  = odd ? reg2[0] : reg1[0];
    const float cue = odd ? 0.0f    : reg1[1];
    const float cuo = odd ? reg2[1] : reg1[2];
    const float c1  = odd ? reg2[2] : reg1[3];
    const float c2c = odd ? reg2[3] : reg1[4];
    const float c3  = odd ? 0.0f    : reg1[5];

    const float4* ug = reinterpret_cast<const float4*>(u);
    const long fmax4 = (long)N * 9 - 1;
    const int gs = gridDim.x;

    // ---- staging maps (R8-verified) ----
    const int row0 = tid / 9,          c0 = tid - row0 * 9;
    const int row1 = (256 + tid) / 9,  c1s = (256 + tid) - row1 * 9;
    const int hrow = (tid - 192) >> 1, hside = tid & 1;

    float4 pf0, pf1; float2 pfh;
    {
        const int r0 = blockIdx.x * 32;
        long g0 = (long)r0 * 9 + tid; if (g0 > fmax4) g0 = fmax4;
        pf0 = ug[g0];
        if (tid < 32) {
            long g1 = (long)r0 * 9 + 256 + tid; if (g1 > fmax4) g1 = fmax4;
            pf1 = ug[g1];
        }
        if (tid >= 192) {
            int rr = r0 + hrow; if (rr > N - 1) rr = N - 1;
            pfh = *reinterpret_cast<const float2*>(u + (size_t)rr * 36 + (hside ? 0 : 34));
        }
    }

    for (int tile = blockIdx.x; tile < ntiles; tile += gs) {
        // ---- stage u_ext / u_bf (cvt_pk); prefetch next (R13-verified) ----
        {
            float* dst = &u_ext[row0 * 40 + 2 + c0 * 4];
            reinterpret_cast<float2*>(dst)[0] = make_float2(pf0.x, pf0.y);
            reinterpret_cast<float2*>(dst)[1] = make_float2(pf0.z, pf0.w);
            reinterpret_cast<unsigned int*>(u_bf)[row0 * 16 + c0] =
                cvt_pk_bf16(pf0.x, pf0.z);
            if (tid < 32) {
                float* dst1 = &u_ext[row1 * 40 + 2 + c1s * 4];
                reinterpret_cast<float2*>(dst1)[0] = make_float2(pf1.x, pf1.y);
                reinterpret_cast<float2*>(dst1)[1] = make_float2(pf1.z, pf1.w);
                reinterpret_cast<unsigned int*>(u_bf)[row1 * 16 + c1s] =
                    cvt_pk_bf16(pf1.x, pf1.z);
            }
            if (tid >= 192)
                *reinterpret_cast<float2*>(&u_ext[hrow * 40 + (hside ? 38 : 0)]) = pfh;

            if (tile + gs < ntiles) {
                const int r0n = (tile + gs) * 32;
                long g0 = (long)r0n * 9 + tid; if (g0 > fmax4) g0 = fmax4;
                pf0 = ug[g0];
                if (tid < 32) {
                    long g1 = (long)r0n * 9 + 256 + tid; if (g1 > fmax4) g1 = fmax4;
                    pf1 = ug[g1];
                }
                if (tid >= 192) {
                    int rr = r0n + hrow; if (rr > N - 1) rr = N - 1;
                    pfh = *reinterpret_cast<const float2*>(u + (size_t)rr * 36 + (hside ? 0 : 34));
                }
            }
        }
        __syncthreads();  // bar1: u ready

        // ---- GEMM1 SWAPPED (R13-verified) ----
#pragma unroll
        for (int rb = 0; rb < 2; ++rb) {
            const short8 a1 = *reinterpret_cast<const short8*>(
                &u_bf[(rb * 16 + ln) * 32 + lg * 8]);
#pragma unroll
            for (int t = 0; t < 2; ++t) {
                const f32x4 h4 = mfma_bf16(b1f[t], a1, bias1v[t]);   // SWAPPED -> h^T
                const unsigned int p0 =
                    cvt_pk_bf16(tanh_pade(h4[0]), tanh_pade(h4[1]));
                const unsigned int p1 =
                    cvt_pk_bf16(tanh_pade(h4[2]), tanh_pade(h4[3]));
                *reinterpret_cast<uint2*>(
                    &h_sh[(rb * 16 + ln) * 136 + nb + t * 16 + lg * 4]) =
                    make_uint2(p0, p1);
            }
        }
        __syncthreads();  // bar2: h ready

        // ---- GEMM2 SWAPPED + in-register epilogue -> res_sh ----
#pragma unroll
        for (int rb = 0; rb < 2; ++rb) {
            const int arow = rb * 16 + ln;
            const bool do8 = (wid == rb);   // wave0 handles tile8@rb0, wave1 @rb1

            f32x4 acc2[2];
            acc2[0] = bias2v[0];
            acc2[1] = bias2v[1];
            f32x4 acc8 = bias8v;

#pragma unroll
            for (int kk = 0; kk < 4; ++kk) {
                const short8 a2 = *reinterpret_cast<const short8*>(
                    &h_sh[arow * 136 + kk * 32 + lg * 8]);
                acc2[0] = mfma_bf16(b2f[0][kk], a2, acc2[0]);   // SWAPPED
                acc2[1] = mfma_bf16(b2f[1][kk], a2, acc2[1]);
                if (do8) {
                    const short8 w8 = *reinterpret_cast<const short8*>(
                        &w8_sh[kk * 512 + l * 8]);
                    acc8 = mfma_bf16(w8, a2, acc8);
                }
            }

            // epilogue (R14/R15-verified formula): main tiles + tile8
#pragma unroll
            for (int tl = 0; tl < 3; ++tl) {
                if (tl == 2 && !do8) continue;
                const f32x4 acc = (tl < 2) ? acc2[tl] : acc8;
                const int g = (tl < 2) ? (2 * wid + tl) : 8;
                const int i = 2 * g + (lg >> 1);

                const float* ub = &u_ext[arow * 40 + 2 * i];
                const float2 v0 = *reinterpret_cast<const float2*>(ub);      // um2, uA
                const float2 v1 = *reinterpret_cast<const float2*>(ub + 2);  // ue,  uo
                const float2 v2 = *reinterpret_cast<const float2*>(ub + 4);  // up2, uC

                const float um2 = v0.x, uA = v0.y;
                const float ue  = v1.x, uo = v1.y;
                const float up2 = v2.x, uC = v2.y;

                const float pa = odd ? ue : um2;   // * uA
                const float pb = odd ? ue : uA;    // * up2

                float res = acc[0] + cb;
                res = fmaf(acc[1], uA, res);
                res = fmaf(acc[2] + cuo, uo, res);
                res = fmaf(acc[3], uC, res);        // even lanes: acc[3]==0
                res = fmaf(c1,  uA * pa,  res);
                res = fmaf(c2c, pb * up2, res);
                res = fmaf(ue,  fmaf(c3, uo, cue), res);

                res_sh[arow * 38 + 2 * i + (odd ? 1 : 0)] = res;
            }
        }
        __syncthreads();  // bar3: res ready

        // ---- copy-out: 576 float2 items, coalesced (R13/R15-verified) ----
        const int r0 = tile * 32;
#pragma unroll
        for (int s = 0; s < 3; ++s) {
            const int w = s * 256 + tid;
            if (w < 576) {
                const int row = w / 18;
                const int p   = w - row * 18;
                const int rg  = r0 + row;
                if (rg < N) {
                    const float2 rv =
                        *reinterpret_cast<const float2*>(&res_sh[row * 38 + 2 * p]);
                    *reinterpret_cast<float2*>(out + (size_t)rg * 36 + 2 * p) = rv;
                }
            }
        }
        __syncthreads();  // bar4: buffers free for next staging
    }
}

extern "C" void kernel_launch(void* const* d_in, const int* in_sizes, int n_in,
                              void* d_out, int out_size, void* d_ws, size_t ws_size,
                              hipStream_t stream) {
    // d_in order: t, u, reg1, reg2, W1, b1, W2a, b2a, W2b, b2b
    const float* u    = (const float*)d_in[1];
    const float* reg1 = (const float*)d_in[2];
    const float* reg2 = (const float*)d_in[3];
    const float* W1   = (const float*)d_in[4];
    const float* b1   = (const float*)d_in[5];
    const float* W2a  = (const float*)d_in[6];
    const float* b2a  = (const float*)d_in[7];
    const float* W2b  = (const float*)d_in[8];
    const float* b2b  = (const float*)d_in[9];
    float* out = (float*)d_out;

    const int N = in_sizes[1] / 36;
    const int ntiles = (N + 31) / 32;
    int grid = ntiles < 1536 ? ntiles : 1536;   // 6 blocks/CU by LDS
    if (grid < 1) grid = 1;
    mixmodel_mfma16<<<grid, 256, 0, stream>>>(u, reg1, reg2, W1, b1,
                                              W2a, b2a, W2b, b2b, out, N, ntiles);
}

// Round 17
// 86.196 us; speedup vs baseline: 1.4957x; 1.1726x over previous
//
#include <hip/hip_runtime.h>
#include <cstddef>

// Block-cooperative MFMA MixModel, 32 rows/tile (R17):
// R13's live-range structure (accs die into LDS immediately; epilogue is a
// SEPARATE phase -- R14/15/16's in-reg epilogue overlapped acc+u+res live
// ranges and spilled 3x) composed from verified pieces only:
//   GEMM1 SWAPPED (R13): h[row=ln][4k] -> tanh_pade -> cvt_pk -> ds_write_b64.
//   GEMM2 SWAPPED (R9/R11): lane (ln,lg) of tile g holds C2[row=ln][16g+4lg..+3];
//     reg tiles {2w,2w+1} (32 VGPR uniform) + tile8 weights/bias in LDS (R16).
//   c2s bf16 [32][148], uint2 writes + bf16 epilogue unpack (R11-verified pair).
//   Epilogue phase: R13 loop with uint2 c2 reads (R11-verified).
//   LDS 29696 B -> 5 blocks/CU, grid 1280.

typedef __attribute__((ext_vector_type(8))) __bf16 bf16x8;
typedef __attribute__((ext_vector_type(8))) short short8;
typedef __attribute__((ext_vector_type(4))) float f32x4;

__device__ __forceinline__ unsigned short f2bf(float f) {
    unsigned int u = __float_as_uint(f);
    unsigned int r = (u + 0x7FFFu + ((u >> 16) & 1u)) >> 16;
    return (unsigned short)r;
}

__device__ __forceinline__ unsigned int cvt_pk_bf16(float lo, float hi) {
    unsigned int r;
    asm("v_cvt_pk_bf16_f32 %0, %1, %2" : "=v"(r) : "v"(lo), "v"(hi));
    return r;
}

__device__ __forceinline__ float bf_lo(unsigned int u) { return __uint_as_float(u << 16); }
__device__ __forceinline__ float bf_hi(unsigned int u) { return __uint_as_float(u & 0xFFFF0000u); }

// --- mfma wrapper: tolerate either V8bf16 or V8i16 builtin signature ---
template <typename A>
__device__ __forceinline__ auto mfma_try(A a, A b, f32x4 c, int)
    -> decltype(__builtin_amdgcn_mfma_f32_16x16x32_bf16(a, b, c, 0, 0, 0)) {
    return __builtin_amdgcn_mfma_f32_16x16x32_bf16(a, b, c, 0, 0, 0);
}
template <typename A>
__device__ __forceinline__ f32x4 mfma_try(A a, A b, f32x4 c, long) {
    return __builtin_amdgcn_mfma_f32_16x16x32_bf16(
        __builtin_bit_cast(short8, a), __builtin_bit_cast(short8, b), c, 0, 0, 0);
}
__device__ __forceinline__ f32x4 mfma_bf16(short8 a, short8 b, f32x4 c) {
    return mfma_try(__builtin_bit_cast(bf16x8, a), __builtin_bit_cast(bf16x8, b), c, 0);
}

__device__ __forceinline__ float tanh_pade(float x) {
    const float t = fminf(fmaxf(x, -3.0f), 3.0f);
    const float s = t * t;
    return __fdividef(t * (27.0f + s), fmaf(9.0f, s, 27.0f));
}

// 144-col internal map (R11/R16-verified): col n = 8q+m
__device__ __forceinline__ float w2_at(const float* W2a, const float* W2b, int k, int n) {
    const int q = n >> 3, m = n & 7;
    if (m < 3)  return W2a[k * 54 + 3 * q + m];
    if (m == 3) return 0.0f;
    return W2b[k * 72 + 4 * q + (m - 4)];
}
__device__ __forceinline__ float b2_at(const float* b2a, const float* b2b, int n) {
    const int q = n >> 3, m = n & 7;
    if (m < 3)  return b2a[3 * q + m];
    if (m == 3) return 0.0f;
    return b2b[4 * q + (m - 4)];
}

__global__ __launch_bounds__(256, 4) void mixmodel_mfma17(
    const float* __restrict__ u,      // N*36
    const float* __restrict__ reg1,   // 6
    const float* __restrict__ reg2,   // 4
    const float* __restrict__ W1,     // 18*128
    const float* __restrict__ b1,     // 128
    const float* __restrict__ W2a,    // 128*54
    const float* __restrict__ b2a,    // 54
    const float* __restrict__ W2b,    // 128*72
    const float* __restrict__ b2b,    // 72
    float* __restrict__ out,          // N*36
    int N, int ntiles)
{
    __shared__ __align__(16) float          u_ext[32 * 40];    // 5120 B
    __shared__ __align__(16) unsigned short h_sh[32 * 136];    // 8704 B (verified layout)
    __shared__ __align__(16) unsigned short u_bf[32 * 32];     // 2048 B
    __shared__ __align__(16) unsigned short c2s[32 * 148];     // 9472 B bf16 (R11-verified)
    __shared__ __align__(16) unsigned short w8_sh[4 * 512];    // 4096 B tile-8 W2 (R16-verified)
    __shared__ __align__(16) float          bias8_sh[64];      // 256 B tile-8 bias
    // total = 29696 B -> 5 blocks/CU

    const int tid = threadIdx.x;
    const int wid = tid >> 6;
    const int l   = tid & 63;
    const int ln  = l & 15;
    const int lg  = l >> 4;
    const int nb  = wid * 32;        // GEMM1 column base

    // ---- one-time LDS init ----
    reinterpret_cast<unsigned int*>(u_bf)[tid]       = 0u;
    reinterpret_cast<unsigned int*>(u_bf)[tid + 256] = 0u;
    {
        // tile-8 W2 fragments in exact consumption order (R16-verified)
        const int kk8 = tid >> 6, l8 = tid & 63;
        const int ln8 = l8 & 15, lg8 = l8 >> 4;
        unsigned int pk[4];
#pragma unroll
        for (int jj = 0; jj < 4; ++jj) {
            const int k0 = kk8 * 32 + lg8 * 8 + 2 * jj;
            pk[jj] = (unsigned int)f2bf(w2_at(W2a, W2b, k0,     128 + ln8)) |
                     ((unsigned int)f2bf(w2_at(W2a, W2b, k0 + 1, 128 + ln8)) << 16);
        }
        unsigned int* dst = reinterpret_cast<unsigned int*>(&w8_sh[kk8 * 512 + l8 * 8]);
        dst[0] = pk[0]; dst[1] = pk[1]; dst[2] = pk[2]; dst[3] = pk[3];
    }
    if (tid < 64) bias8_sh[tid] = b2_at(b2a, b2b, 128 + tid);
    __syncthreads();

    // ---- GEMM1 weights (swapped; R13-verified) ----
    short8 b1f[2];
    f32x4 bias1v[2];
#pragma unroll
    for (int t = 0; t < 2; ++t) {
        const int n = nb + t * 16 + ln;
        short8 v;
#pragma unroll
        for (int j = 0; j < 8; ++j) {
            const int k = lg * 8 + j;
            const float w = (k < 18) ? W1[k * 128 + n] : 0.0f;
            v[j] = (short)f2bf(w);
        }
        b1f[t] = v;
        bias1v[t] = *reinterpret_cast<const f32x4*>(&b1[nb + t * 16 + lg * 4]);
    }

    // ---- GEMM2 register weights: tiles {2w, 2w+1} (R11 map, R16 split) ----
    short8 b2f[2][4];
    f32x4 bias2v[2];
#pragma unroll
    for (int tl = 0; tl < 2; ++tl) {
        const int g  = 2 * wid + tl;
        const int nf = 16 * g + ln;
#pragma unroll
        for (int kk = 0; kk < 4; ++kk) {
            short8 w2;
#pragma unroll
            for (int j = 0; j < 8; ++j)
                w2[j] = (short)f2bf(w2_at(W2a, W2b, kk * 32 + lg * 8 + j, nf));
            b2f[tl][kk] = w2;
        }
        f32x4 bv;
#pragma unroll
        for (int r = 0; r < 4; ++r)
            bv[r] = b2_at(b2a, b2b, 16 * g + 4 * lg + r);
        bias2v[tl] = bv;
    }

    // ---- regression coefficients (wave-uniform -> SGPR; R13 epilogue form) ----
    const float r10 = reg1[0], r11 = reg1[1], r12 = reg1[2];
    const float r13 = reg1[3], r14 = reg1[4], r15 = reg1[5];
    const float r20 = reg2[0], r21 = reg2[1], r22 = reg2[2], r23 = reg2[3];

    const float4* ug = reinterpret_cast<const float4*>(u);
    const long fmax4 = (long)N * 9 - 1;
    const int gs = gridDim.x;

    // ---- staging maps (R8-verified) ----
    const int row0 = tid / 9,          c0 = tid - row0 * 9;
    const int row1 = (256 + tid) / 9,  c1s = (256 + tid) - row1 * 9;
    const int hrow = (tid - 192) >> 1, hside = tid & 1;

    float4 pf0, pf1; float2 pfh;
    {
        const int r0 = blockIdx.x * 32;
        long g0 = (long)r0 * 9 + tid; if (g0 > fmax4) g0 = fmax4;
        pf0 = ug[g0];
        if (tid < 32) {
            long g1 = (long)r0 * 9 + 256 + tid; if (g1 > fmax4) g1 = fmax4;
            pf1 = ug[g1];
        }
        if (tid >= 192) {
            int rr = r0 + hrow; if (rr > N - 1) rr = N - 1;
            pfh = *reinterpret_cast<const float2*>(u + (size_t)rr * 36 + (hside ? 0 : 34));
        }
    }

    for (int tile = blockIdx.x; tile < ntiles; tile += gs) {
        // ---- stage u_ext / u_bf (cvt_pk); prefetch next (R13-verified) ----
        {
            float* dst = &u_ext[row0 * 40 + 2 + c0 * 4];
            reinterpret_cast<float2*>(dst)[0] = make_float2(pf0.x, pf0.y);
            reinterpret_cast<float2*>(dst)[1] = make_float2(pf0.z, pf0.w);
            reinterpret_cast<unsigned int*>(u_bf)[row0 * 16 + c0] =
                cvt_pk_bf16(pf0.x, pf0.z);
            if (tid < 32) {
                float* dst1 = &u_ext[row1 * 40 + 2 + c1s * 4];
                reinterpret_cast<float2*>(dst1)[0] = make_float2(pf1.x, pf1.y);
                reinterpret_cast<float2*>(dst1)[1] = make_float2(pf1.z, pf1.w);
                reinterpret_cast<unsigned int*>(u_bf)[row1 * 16 + c1s] =
                    cvt_pk_bf16(pf1.x, pf1.z);
            }
            if (tid >= 192)
                *reinterpret_cast<float2*>(&u_ext[hrow * 40 + (hside ? 38 : 0)]) = pfh;

            if (tile + gs < ntiles) {
                const int r0n = (tile + gs) * 32;
                long g0 = (long)r0n * 9 + tid; if (g0 > fmax4) g0 = fmax4;
                pf0 = ug[g0];
                if (tid < 32) {
                    long g1 = (long)r0n * 9 + 256 + tid; if (g1 > fmax4) g1 = fmax4;
                    pf1 = ug[g1];
                }
                if (tid >= 192) {
                    int rr = r0n + hrow; if (rr > N - 1) rr = N - 1;
                    pfh = *reinterpret_cast<const float2*>(u + (size_t)rr * 36 + (hside ? 0 : 34));
                }
            }
        }
        __syncthreads();  // bar1: u ready

        // ---- GEMM1 SWAPPED (R13-verified) ----
#pragma unroll
        for (int rb = 0; rb < 2; ++rb) {
            const short8 a1 = *reinterpret_cast<const short8*>(
                &u_bf[(rb * 16 + ln) * 32 + lg * 8]);
#pragma unroll
            for (int t = 0; t < 2; ++t) {
                const f32x4 h4 = mfma_bf16(b1f[t], a1, bias1v[t]);   // SWAPPED -> h^T
                const unsigned int p0 =
                    cvt_pk_bf16(tanh_pade(h4[0]), tanh_pade(h4[1]));
                const unsigned int p1 =
                    cvt_pk_bf16(tanh_pade(h4[2]), tanh_pade(h4[3]));
                *reinterpret_cast<uint2*>(
                    &h_sh[(rb * 16 + ln) * 136 + nb + t * 16 + lg * 4]) =
                    make_uint2(p0, p1);
            }
        }
        __syncthreads();  // bar2: h ready

        // ---- GEMM2 SWAPPED: accs die into c2s immediately (R13 live-range form) ----
#pragma unroll
        for (int rb = 0; rb < 2; ++rb) {
            const int arow = rb * 16 + ln;
            const bool do8 = (wid == rb);
            const int rbase = arow * 148;

            f32x4 acc2[2];
            acc2[0] = bias2v[0];
            acc2[1] = bias2v[1];
            f32x4 acc8;
            if (do8) acc8 = *reinterpret_cast<const f32x4*>(&bias8_sh[4 * lg]);

#pragma unroll
            for (int kk = 0; kk < 4; ++kk) {
                const short8 a2 = *reinterpret_cast<const short8*>(
                    &h_sh[arow * 136 + kk * 32 + lg * 8]);
                acc2[0] = mfma_bf16(b2f[0][kk], a2, acc2[0]);   // SWAPPED
                acc2[1] = mfma_bf16(b2f[1][kk], a2, acc2[1]);
                if (do8) {
                    const short8 w8 = *reinterpret_cast<const short8*>(
                        &w8_sh[kk * 512 + l * 8]);
                    acc8 = mfma_bf16(w8, a2, acc8);
                }
            }

            // c2s writes: R11-verified uint2 bf16 pattern (col = 16g+4lg)
#pragma unroll
            for (int tl = 0; tl < 2; ++tl) {
                const unsigned int lo = cvt_pk_bf16(acc2[tl][0], acc2[tl][1]);
                const unsigned int hi = cvt_pk_bf16(acc2[tl][2], acc2[tl][3]);
                *reinterpret_cast<uint2*>(
                    &c2s[rbase + 16 * (2 * wid + tl) + 4 * lg]) = make_uint2(lo, hi);
            }
            if (do8) {
                const unsigned int lo = cvt_pk_bf16(acc8[0], acc8[1]);
                const unsigned int hi = cvt_pk_bf16(acc8[2], acc8[3]);
                *reinterpret_cast<uint2*>(
                    &c2s[rbase + 128 + 4 * lg]) = make_uint2(lo, hi);
            }
        }
        __syncthreads();  // bar3: c2 ready

        // ---- epilogue phase (R13 structure, R11-verified bf16 unpack) ----
        const int r0 = tile * 32;
#pragma unroll
        for (int s = 0; s < 3; ++s) {
            const int w = s * 256 + tid;
            if (w < 576) {
                const int row = w / 18;
                const int i   = w - row * 18;
                const int rg  = r0 + row;

                const float2 v0 = *reinterpret_cast<const float2*>(&u_ext[row * 40 + 2 * i]);
                const float2 v1 = *reinterpret_cast<const float2*>(&u_ext[row * 40 + 2 * i + 2]);
                const float2 v2 = *reinterpret_cast<const float2*>(&u_ext[row * 40 + 2 * i + 4]);
                const uint2  q0 = *reinterpret_cast<const uint2*>(&c2s[row * 148 + 8 * i]);
                const uint2  q1 = *reinterpret_cast<const uint2*>(&c2s[row * 148 + 8 * i + 4]);

                const float um2 = v0.x, uA = v0.y;
                const float ue  = v1.x, uo = v1.y;
                const float up2 = v2.x, uC = v2.y;

                const float o00 = bf_lo(q0.x), o01 = bf_hi(q0.x), o02 = bf_lo(q0.y);
                const float o10 = bf_lo(q1.x), o11 = bf_hi(q1.x);
                const float o12 = bf_lo(q1.y), o13 = bf_hi(q1.y);

                const float oe = o00 + o01 * uA + o02 * uo;
                const float oo = o10 + o11 * uA + o12 * uo + o13 * uC;

                float re = r10;
                re = fmaf(r11, ue,       re);
                re = fmaf(r12, uo,       re);
                re = fmaf(r13, um2 * uA, re);
                re = fmaf(r14, uA * up2, re);
                re = fmaf(r15, ue * uo,  re);

                float ro = r20;
                ro = fmaf(r21, uo,       ro);
                ro = fmaf(r22, uA * ue,  ro);
                ro = fmaf(r23, ue * up2, ro);

                if (rg < N)
                    *reinterpret_cast<float2*>(out + (size_t)rg * 36 + 2 * i) =
                        make_float2(oe + re, oo + ro);
            }
        }
        __syncthreads();  // bar4: buffers free for next staging
    }
}

extern "C" void kernel_launch(void* const* d_in, const int* in_sizes, int n_in,
                              void* d_out, int out_size, void* d_ws, size_t ws_size,
                              hipStream_t stream) {
    // d_in order: t, u, reg1, reg2, W1, b1, W2a, b2a, W2b, b2b
    const float* u    = (const float*)d_in[1];
    const float* reg1 = (const float*)d_in[2];
    const float* reg2 = (const float*)d_in[3];
    const float* W1   = (const float*)d_in[4];
    const float* b1   = (const float*)d_in[5];
    const float* W2a  = (const float*)d_in[6];
    const float* b2a  = (const float*)d_in[7];
    const float* W2b  = (const float*)d_in[8];
    const float* b2b  = (const float*)d_in[9];
    float* out = (float*)d_out;

    const int N = in_sizes[1] / 36;
    const int ntiles = (N + 31) / 32;
    int grid = ntiles < 1280 ? ntiles : 1280;   // 5 blocks/CU by LDS
    if (grid < 1) grid = 1;
    mixmodel_mfma17<<<grid, 256, 0, stream>>>(u, reg1, reg2, W1, b1,
                                              W2a, b2a, W2b, b2b, out, N, ntiles);
}